// Round 10
// baseline (496.671 us; speedup 1.0000x reference)
//
#include <hip/hip_runtime.h>
#include <hip/hip_bf16.h>
#include <cstdint>
#include <cstddef>

#define I_      100
#define J_      8
#define D_IN    768
#define D_H     64
#define N_NODES 160000
#define N_HE    320000
#define N_INC   1600000
#define N_CELLS 800
#define VOCAB   30000

#define NRANGE   256
#define NPR      625
#define SLAB     8192            // per-range bucket/csr slab (Poisson(6250), 24 sigma)
#define NCHUNK   1000            // Ka/Kc scatter chunks (4 blocks/CU latency hiding)
#define EPB      (N_INC / NCHUNK)   // 1600

typedef unsigned short u16;
using short8 = __attribute__((ext_vector_type(8))) short;
using f32x4  = __attribute__((ext_vector_type(4))) float;

__device__ __forceinline__ float bf2f(u16 u) {
    union { uint32_t i; float f; } x; x.i = ((uint32_t)u) << 16; return x.f;
}
__device__ __forceinline__ u16 f2bf(float f) {
    union { float f; uint32_t i; } x; x.f = f;
    uint32_t b = x.i;
    b += 0x7FFFu + ((b >> 16) & 1u);
    return (u16)(b >> 16);
}
__device__ __forceinline__ float lo_bf(uint32_t u) {
    union { uint32_t i; float f; } x; x.i = u << 16; return x.f;
}
__device__ __forceinline__ float hi_bf(uint32_t u) {
    union { uint32_t i; float f; } x; x.i = u & 0xFFFF0000u; return x.f;
}
__device__ __forceinline__ uint32_t pack_bf2(float a, float b) {
    return (uint32_t)f2bf(a) | ((uint32_t)f2bf(b) << 16);
}

// grid-partition constants
#define G_OFF_HE   (N_INC / 256)        // 6250
#define G_OFF_CELL (N_NODES / 256)      // 625
#define G_CONV_BIG ((D_IN * 64) / 256)  // 192
#define G_CONV_SM  ((64 * 64) / 256)    // 16
#define G_KA       NCHUNK               // 1000 per-chunk range histograms
#define G_KB1      256                  // per-range column scans
#define G_KC       NCHUNK               // 1000 bucket scatter
#define G_KD       256                  // per-range CSR hist+scan+place
#define G_PGEMM    ((VOCAB + 63) / 64)  // 469
#define G_XT       (N_NODES / 64)       // 2500
#define G_X0       ((I_ * J_ + 63) / 64)// 13

// gather phases: 4x grid-stride (fewer, longer blocks: cut wg-dispatch overhead)
#define HGRP       (N_HE / 32)          // 10000 hedge groups (32 hedges each)
#define HED_BLK    (HGRP / 4)           // 2500 blocks x 4 groups
#define NGRP       (N_NODES / 32)       // 5000 node groups
#define NOD_BLK    (NGRP / 4)           // 1250 blocks x 4 groups
#define NXT_BLK    (NGRP / 4)           // 1250 blocks x 4 tiles

// ---------------------------------------------------------------------------
__device__ __forceinline__ void dev_offsets(int bid, const int* __restrict__ sorted,
                                            int n, int nbins, int* __restrict__ off) {
    int i = bid * 256 + threadIdx.x;
    if (i >= n) return;
    int cur = sorted[i];
    int prev = (i == 0) ? -1 : sorted[i - 1];
    for (int b = prev + 1; b <= cur; ++b) off[b] = i;
    if (i == n - 1) {
        for (int b = cur + 1; b <= nbins; ++b) off[b] = n;
    }
}

__device__ __forceinline__ void dev_convT(int bid, const float* __restrict__ B,
                                          u16* __restrict__ Bt, int K) {
    int g = bid * 256 + threadIdx.x;
    if (g >= K * 64) return;
    int k = g >> 6, n = g & 63;
    Bt[(size_t)n * K + k] = f2bf(B[g]);
}

// ---------------------------------------------------------------------------
// bucket-sort CSR build: chunk-contiguous writes throughout, no global atomics
// ---------------------------------------------------------------------------
// Ka: per-chunk histogram of node ranges -> counts[chunk][256]
__device__ __forceinline__ void dev_ka(int bid, const int* __restrict__ inc_node,
                                       int* __restrict__ counts, int* __restrict__ lds) {
    int tid = threadIdx.x;
    lds[tid] = 0;
    __syncthreads();
    int s = bid * EPB, e = s + EPB;
    for (int i = s + tid; i < e; i += 256)
        atomicAdd(&lds[(unsigned)inc_node[i] / NPR], 1);
    __syncthreads();
    counts[bid * NRANGE + tid] = lds[tid];
}

// Kb1: one block per range r: scan counts[c][r] over c=0..NCHUNK-1
__device__ __forceinline__ void dev_kb1(int r, const int* __restrict__ counts,
                                        int* __restrict__ chunk_off,
                                        int* __restrict__ range_total,
                                        int* __restrict__ lds) {
    int tid = threadIdx.x;
    int c0 = tid * 4;
    int v0 = (c0     < NCHUNK) ? counts[(c0    ) * NRANGE + r] : 0;
    int v1 = (c0 + 1 < NCHUNK) ? counts[(c0 + 1) * NRANGE + r] : 0;
    int v2 = (c0 + 2 < NCHUNK) ? counts[(c0 + 2) * NRANGE + r] : 0;
    int v3 = (c0 + 3 < NCHUNK) ? counts[(c0 + 3) * NRANGE + r] : 0;
    int s = v0 + v1 + v2 + v3;
    lds[tid] = s;
    __syncthreads();
    #pragma unroll
    for (int d = 1; d < 256; d <<= 1) {
        int t = (tid >= d) ? lds[tid - d] : 0;
        __syncthreads();
        lds[tid] += t;
        __syncthreads();
    }
    int run = lds[tid] - s;
    if (c0     < NCHUNK) { chunk_off[(c0    ) * NRANGE + r] = run; run += v0; }
    if (c0 + 1 < NCHUNK) { chunk_off[(c0 + 1) * NRANGE + r] = run; run += v1; }
    if (c0 + 2 < NCHUNK) { chunk_off[(c0 + 2) * NRANGE + r] = run; run += v2; }
    if (c0 + 3 < NCHUNK) { chunk_off[(c0 + 3) * NRANGE + r] = run; run += v3; }
    if (tid == 255) range_total[r] = lds[255];
}

// Kc: scatter pairs into per-range slabs (chunk-contiguous writes)
__device__ __forceinline__ void dev_kc(int bid, const int* __restrict__ inc_node,
                                       const int* __restrict__ inc_hedge,
                                       const int* __restrict__ chunk_off,
                                       int2* __restrict__ bucket, int* __restrict__ lds) {
    int tid = threadIdx.x;
    int* co  = lds;
    int* cur = lds + 256;
    co[tid]  = tid * SLAB + chunk_off[bid * NRANGE + tid];
    cur[tid] = 0;
    __syncthreads();
    int s = bid * EPB, e = s + EPB;
    for (int i = s + tid; i < e; i += 256) {
        int v = inc_node[i];
        int h = inc_hedge[i];
        int rg = (unsigned)v / NPR;
        int rank = atomicAdd(&cur[rg], 1);
        bucket[co[rg] + rank] = make_int2(v, h);
    }
}

// Kd: per-range exact CSR placement; writes node_off + node_deg (all LDS-local)
// lds layout: hist[768] | tsum[256] | cur[768]  (1792 ints)
__device__ __forceinline__ void dev_kd(int r, const int2* __restrict__ bucket,
                                       const int* __restrict__ range_total,
                                       int* __restrict__ node_off, int* __restrict__ node_deg,
                                       int* __restrict__ csr, int* __restrict__ lds) {
    int tid = threadIdx.x;
    int* hist = lds;
    int* tsum = lds + 768;
    int* cur  = lds + 1024;
    for (int i = tid; i < 768; i += 256) { hist[i] = 0; cur[i] = 0; }
    __syncthreads();
    int lo = r * NPR;
    int pb = r * SLAB;
    int pe = pb + range_total[r];
    for (int i = pb + tid; i < pe; i += 256)
        atomicAdd(&hist[bucket[i].x - lo], 1);
    __syncthreads();
    int b3 = tid * 3;
    int a0 = hist[b3], a1 = hist[b3 + 1], a2 = hist[b3 + 2];
    int s = a0 + a1 + a2;
    tsum[tid] = s;
    __syncthreads();
    #pragma unroll
    for (int d = 1; d < 256; d <<= 1) {
        int t = (tid >= d) ? tsum[tid - d] : 0;
        __syncthreads();
        tsum[tid] += t;
        __syncthreads();
    }
    int excl = tsum[tid] - s;
    hist[b3]     = excl;
    hist[b3 + 1] = excl + a0;
    hist[b3 + 2] = excl + a0 + a1;
    __syncthreads();
    for (int v = tid; v < NPR; v += 256) {
        int h0 = hist[v];
        node_off[lo + v] = pb + h0;
        node_deg[lo + v] = hist[v + 1] - h0;   // hist[625] = range total (valid)
    }
    for (int i = pb + tid; i < pe; i += 256) {
        int2 p = bucket[i];
        int l = p.x - lo;
        int k = atomicAdd(&cur[l], 1);
        csr[pb + hist[l] + k] = p.y;
    }
}

// ---------------------------------------------------------------------------
// R8 row-split barrier-free MFMA GEMM: one wave owns 16 rows x 64 cols
// ---------------------------------------------------------------------------
template <int BF16_OUT, int GATHER, int KK>
__device__ __forceinline__ void dev_gemm_direct(int wid, const float* __restrict__ A,
                                                const int* __restrict__ tok,
                                                const u16* __restrict__ Bt,
                                                const float* __restrict__ bias,
                                                void* __restrict__ C, int M) {
    int lane = threadIdx.x & 63;
    int m16 = lane & 15, q = lane >> 4;
    int base = wid << 4;
    if (base >= M) return;
    int row = base + m16;
    const float* arow = GATHER ? (A + ((size_t)tok[row] << 6))
                               : (A + (size_t)row * KK);

    f32x4 acc0 = {0.f, 0.f, 0.f, 0.f};
    f32x4 acc1 = {0.f, 0.f, 0.f, 0.f};
    f32x4 acc2 = {0.f, 0.f, 0.f, 0.f};
    f32x4 acc3 = {0.f, 0.f, 0.f, 0.f};

    #pragma unroll 2
    for (int kt = 0; kt < KK; kt += 32) {
        const float* ap = arow + kt + q * 8;
        float4 av0 = *reinterpret_cast<const float4*>(ap);
        float4 av1 = *reinterpret_cast<const float4*>(ap + 4);
        short8 a;
        a[0] = (short)f2bf(av0.x); a[1] = (short)f2bf(av0.y);
        a[2] = (short)f2bf(av0.z); a[3] = (short)f2bf(av0.w);
        a[4] = (short)f2bf(av1.x); a[5] = (short)f2bf(av1.y);
        a[6] = (short)f2bf(av1.z); a[7] = (short)f2bf(av1.w);
        const u16* bp = Bt + (size_t)m16 * KK + kt + q * 8;
        short8 b0 = *reinterpret_cast<const short8*>(bp);
        short8 b1 = *reinterpret_cast<const short8*>(bp + (size_t)16 * KK);
        short8 b2 = *reinterpret_cast<const short8*>(bp + (size_t)32 * KK);
        short8 b3 = *reinterpret_cast<const short8*>(bp + (size_t)48 * KK);
        acc0 = __builtin_amdgcn_mfma_f32_16x16x32_bf16(a, b0, acc0, 0, 0, 0);
        acc1 = __builtin_amdgcn_mfma_f32_16x16x32_bf16(a, b1, acc1, 0, 0, 0);
        acc2 = __builtin_amdgcn_mfma_f32_16x16x32_bf16(a, b2, acc2, 0, 0, 0);
        acc3 = __builtin_amdgcn_mfma_f32_16x16x32_bf16(a, b3, acc3, 0, 0, 0);
    }

    f32x4 accs[4] = {acc0, acc1, acc2, acc3};
    #pragma unroll
    for (int r = 0; r < 4; ++r) {
        int gr = base + q * 4 + r;
        #pragma unroll
        for (int j = 0; j < 4; ++j) {
            int col = j * 16 + m16;
            float v = accs[j][r];
            if (!BF16_OUT) v += bias[col];
            if (BF16_OUT)
                ((u16*)C)[(size_t)gr * 64 + col] = f2bf(v);
            else
                ((float*)C)[(size_t)gr * 64 + col] = v;
        }
    }
}

// ---------------------------------------------------------------------------
// hedge_sum: one 8-lane subgroup per hedge (8 hedges/wave), 2-way MLP unroll
// grp indexes 32-hedge groups (exact: N_HE = 10000*32)
// ---------------------------------------------------------------------------
__device__ __forceinline__ void dev_hedge_sum(int grp, const int* __restrict__ inc_node,
                                              const int* __restrict__ he_off,
                                              const u16* __restrict__ xt,
                                              u16* __restrict__ he) {
    int w = (grp * 256 + (int)threadIdx.x) >> 6;
    int lane = threadIdx.x & 63;
    int sub = lane >> 3;
    int c8 = (lane & 7) << 3;
    int hedge = w * 8 + sub;
    if (hedge >= N_HE) return;
    int s = he_off[hedge], e = he_off[hedge + 1];

    float a0 = 0.f, a1 = 0.f, a2 = 0.f, a3 = 0.f;
    float a4 = 0.f, a5 = 0.f, a6 = 0.f, a7 = 0.f;
    float b0 = 0.f, b1 = 0.f, b2 = 0.f, b3 = 0.f;
    float b4 = 0.f, b5 = 0.f, b6 = 0.f, b7 = 0.f;

    int j = s;
    if ((e - s) & 1) {
        uint4 d = *reinterpret_cast<const uint4*>(xt + (((size_t)inc_node[j]) << 6) + c8);
        a0 += lo_bf(d.x); a1 += hi_bf(d.x);
        a2 += lo_bf(d.y); a3 += hi_bf(d.y);
        a4 += lo_bf(d.z); a5 += hi_bf(d.z);
        a6 += lo_bf(d.w); a7 += hi_bf(d.w);
        ++j;
    }
    int i0 = 0, i1 = 0;
    if (j < e) { i0 = inc_node[j]; i1 = inc_node[j + 1]; }
    for (; j < e; j += 2) {
        int c0 = i0, c1 = i1;
        if (j + 2 < e) { i0 = inc_node[j + 2]; i1 = inc_node[j + 3]; }
        uint4 d0 = *reinterpret_cast<const uint4*>(xt + (((size_t)c0) << 6) + c8);
        uint4 d1 = *reinterpret_cast<const uint4*>(xt + (((size_t)c1) << 6) + c8);
        a0 += lo_bf(d0.x); a1 += hi_bf(d0.x);
        a2 += lo_bf(d0.y); a3 += hi_bf(d0.y);
        a4 += lo_bf(d0.z); a5 += hi_bf(d0.z);
        a6 += lo_bf(d0.w); a7 += hi_bf(d0.w);
        b0 += lo_bf(d1.x); b1 += hi_bf(d1.x);
        b2 += lo_bf(d1.y); b3 += hi_bf(d1.y);
        b4 += lo_bf(d1.z); b5 += hi_bf(d1.z);
        b6 += lo_bf(d1.w); b7 += hi_bf(d1.w);
    }
    a0 += b0; a1 += b1; a2 += b2; a3 += b3;
    a4 += b4; a5 += b5; a6 += b6; a7 += b7;

    float inv = (e > s) ? 1.f / (float)(e - s) : 0.f;
    uint4 o;
    o.x = pack_bf2(a0 * inv, a1 * inv);
    o.y = pack_bf2(a2 * inv, a3 * inv);
    o.z = pack_bf2(a4 * inv, a5 * inv);
    o.w = pack_bf2(a6 * inv, a7 * inv);
    *reinterpret_cast<uint4*>(he + (((size_t)hedge) << 6) + c8) = o;
}

// node_sum core: returns the 8 h1/gx values for this lane's 8 cols
__device__ __forceinline__ void dev_node_core(int node, const int* __restrict__ csr,
                                              const int* __restrict__ node_off,
                                              const int* __restrict__ node_deg,
                                              const u16* __restrict__ he,
                                              const float* __restrict__ bias,
                                              const float* __restrict__ P,
                                              const int* __restrict__ tok,
                                              int c8, float* __restrict__ o) {
    int s = node_off[node];
    int e = s + node_deg[node];

    float a0 = 0.f, a1 = 0.f, a2 = 0.f, a3 = 0.f;
    float a4 = 0.f, a5 = 0.f, a6 = 0.f, a7 = 0.f;
    float b0 = 0.f, b1 = 0.f, b2 = 0.f, b3 = 0.f;
    float b4 = 0.f, b5 = 0.f, b6 = 0.f, b7 = 0.f;

    int j = s;
    if ((e - s) & 1) {
        uint4 d = *reinterpret_cast<const uint4*>(he + (((size_t)csr[j]) << 6) + c8);
        a0 += lo_bf(d.x); a1 += hi_bf(d.x);
        a2 += lo_bf(d.y); a3 += hi_bf(d.y);
        a4 += lo_bf(d.z); a5 += hi_bf(d.z);
        a6 += lo_bf(d.w); a7 += hi_bf(d.w);
        ++j;
    }
    int i0 = 0, i1 = 0;
    if (j < e) { i0 = csr[j]; i1 = csr[j + 1]; }
    for (; j < e; j += 2) {
        int c0 = i0, c1 = i1;
        if (j + 2 < e) { i0 = csr[j + 2]; i1 = csr[j + 3]; }
        uint4 d0 = *reinterpret_cast<const uint4*>(he + (((size_t)c0) << 6) + c8);
        uint4 d1 = *reinterpret_cast<const uint4*>(he + (((size_t)c1) << 6) + c8);
        a0 += lo_bf(d0.x); a1 += hi_bf(d0.x);
        a2 += lo_bf(d0.y); a3 += hi_bf(d0.y);
        a4 += lo_bf(d0.z); a5 += hi_bf(d0.z);
        a6 += lo_bf(d0.w); a7 += hi_bf(d0.w);
        b0 += lo_bf(d1.x); b1 += hi_bf(d1.x);
        b2 += lo_bf(d1.y); b3 += hi_bf(d1.y);
        b4 += lo_bf(d1.z); b5 += hi_bf(d1.z);
        b6 += lo_bf(d1.w); b7 += hi_bf(d1.w);
    }
    a0 += b0; a1 += b1; a2 += b2; a3 += b3;
    a4 += b4; a5 += b5; a6 += b6; a7 += b7;

    float inv = (e > s) ? 1.f / (float)(e - s) : 0.f;
    const float* nfp = P + (((size_t)tok[node]) << 6) + c8;
    float4 nv0 = *reinterpret_cast<const float4*>(nfp);
    float4 nv1 = *reinterpret_cast<const float4*>(nfp + 4);
    o[0] = fmaxf(fmaf(a0, inv, bias[c8 + 0]), 0.f) + nv0.x;
    o[1] = fmaxf(fmaf(a1, inv, bias[c8 + 1]), 0.f) + nv0.y;
    o[2] = fmaxf(fmaf(a2, inv, bias[c8 + 2]), 0.f) + nv0.z;
    o[3] = fmaxf(fmaf(a3, inv, bias[c8 + 3]), 0.f) + nv0.w;
    o[4] = fmaxf(fmaf(a4, inv, bias[c8 + 4]), 0.f) + nv1.x;
    o[5] = fmaxf(fmaf(a5, inv, bias[c8 + 5]), 0.f) + nv1.y;
    o[6] = fmaxf(fmaf(a6, inv, bias[c8 + 6]), 0.f) + nv1.z;
    o[7] = fmaxf(fmaf(a7, inv, bias[c8 + 7]), 0.f) + nv1.w;
}

// ---------------------------------------------------------------------------
// P4 fused: node_sum L1 -> LDS bf16 tile -> th2 MFMA -> xt  (skips hbuf)
// 4 tiles/block (grid-stride): 32 nodes/tile; waves 0-1 run the MFMA
// ---------------------------------------------------------------------------
__global__ __launch_bounds__(256) void k_node_xt(const int* __restrict__ csr,
                                                 const int* __restrict__ node_off,
                                                 const int* __restrict__ node_deg,
                                                 const u16* __restrict__ he,
                                                 const float* __restrict__ bias,
                                                 const float* __restrict__ P,
                                                 const int* __restrict__ tok,
                                                 const u16* __restrict__ Bt,
                                                 u16* __restrict__ xt) {
    __shared__ u16 h1s[32][72];   // +8 pad: row stride 144B breaks 128B bank alias
    int tid = threadIdx.x;
    int w = tid >> 6;
    int lane = tid & 63;
    int sub = lane >> 3;
    int c8 = (lane & 7) << 3;
    int rowib = w * 8 + sub;                    // 0..31

    for (int t = 0; t < 4; ++t) {
        int tile = blockIdx.x + t * NXT_BLK;    // 0..4999 (exact)
        int node = tile * 32 + rowib;

        float o[8];
        dev_node_core(node, csr, node_off, node_deg, he, bias, P, tok, c8, o);

        uint4 pk;
        pk.x = pack_bf2(o[0], o[1]);
        pk.y = pack_bf2(o[2], o[3]);
        pk.z = pack_bf2(o[4], o[5]);
        pk.w = pack_bf2(o[6], o[7]);
        *reinterpret_cast<uint4*>(&h1s[rowib][c8]) = pk;
        __syncthreads();

        if (w < 2) {
            int m16 = lane & 15, q = lane >> 4;
            int base = w * 16;
            f32x4 acc0 = {0.f, 0.f, 0.f, 0.f};
            f32x4 acc1 = {0.f, 0.f, 0.f, 0.f};
            f32x4 acc2 = {0.f, 0.f, 0.f, 0.f};
            f32x4 acc3 = {0.f, 0.f, 0.f, 0.f};
            #pragma unroll
            for (int kt = 0; kt < 64; kt += 32) {
                short8 a = *reinterpret_cast<const short8*>(&h1s[base + m16][kt + q * 8]);
                const u16* bp = Bt + (size_t)m16 * 64 + kt + q * 8;
                short8 b0 = *reinterpret_cast<const short8*>(bp);
                short8 b1 = *reinterpret_cast<const short8*>(bp + (size_t)16 * 64);
                short8 b2 = *reinterpret_cast<const short8*>(bp + (size_t)32 * 64);
                short8 b3 = *reinterpret_cast<const short8*>(bp + (size_t)48 * 64);
                acc0 = __builtin_amdgcn_mfma_f32_16x16x32_bf16(a, b0, acc0, 0, 0, 0);
                acc1 = __builtin_amdgcn_mfma_f32_16x16x32_bf16(a, b1, acc1, 0, 0, 0);
                acc2 = __builtin_amdgcn_mfma_f32_16x16x32_bf16(a, b2, acc2, 0, 0, 0);
                acc3 = __builtin_amdgcn_mfma_f32_16x16x32_bf16(a, b3, acc3, 0, 0, 0);
            }
            f32x4 accs[4] = {acc0, acc1, acc2, acc3};
            #pragma unroll
            for (int r = 0; r < 4; ++r) {
                int gr = tile * 32 + base + q * 4 + r;
                #pragma unroll
                for (int jj = 0; jj < 4; ++jj) {
                    int col = jj * 16 + m16;
                    xt[(size_t)gr * 64 + col] = f2bf(accs[jj][r]);
                }
            }
        }
        __syncthreads();   // protect h1s reuse next iteration
    }
}

// node_sum standalone (L2): 4 groups/block, writes f32 gx rows
__global__ __launch_bounds__(256) void k_node_sum(const int* __restrict__ csr,
                                                  const int* __restrict__ node_off,
                                                  const int* __restrict__ node_deg,
                                                  const u16* __restrict__ he,
                                                  const float* __restrict__ bias,
                                                  const float* __restrict__ P,
                                                  const int* __restrict__ tok,
                                                  float* __restrict__ out) {
    int lane = threadIdx.x & 63;
    int sub = lane >> 3;
    int c8 = (lane & 7) << 3;
    for (int t = 0; t < 4; ++t) {
        int grp = blockIdx.x + t * NOD_BLK;     // 0..4999 (exact)
        int w = (grp * 256 + (int)threadIdx.x) >> 6;
        int node = w * 8 + sub;
        float o[8];
        dev_node_core(node, csr, node_off, node_deg, he, bias, P, tok, c8, o);
        float* op = out + (((size_t)node) << 6) + c8;
        float4 o0 = make_float4(o[0], o[1], o[2], o[3]);
        float4 o1 = make_float4(o[4], o[5], o[6], o[7]);
        *reinterpret_cast<float4*>(op) = o0;
        *reinterpret_cast<float4*>(op + 4) = o1;
    }
}

// ---------------------------------------------------------------------------
// phase mega-kernels (tail sub-kernels get LOWEST blockIdx so they start at t=0)
// ---------------------------------------------------------------------------
// P0: Ka + convT x4
__global__ __launch_bounds__(256) void k_p0(const float* __restrict__ fhi_w,
                                            const float* __restrict__ fin_w,
                                            const float* __restrict__ th1,
                                            const float* __restrict__ th2,
                                            u16* __restrict__ Bt_fhi, u16* __restrict__ Bt_fin,
                                            u16* __restrict__ Bt_th1, u16* __restrict__ Bt_th2,
                                            const int* __restrict__ inc_node,
                                            int* __restrict__ counts) {
    __shared__ int lds[256];
    int bid = blockIdx.x;
    if (bid < G_KA) { dev_ka(bid, inc_node, counts, lds); return; }
    bid -= G_KA;
    if (bid < G_CONV_BIG) { dev_convT(bid, fhi_w, Bt_fhi, D_IN); return; }
    bid -= G_CONV_BIG;
    if (bid < G_CONV_BIG) { dev_convT(bid, fin_w, Bt_fin, D_IN); return; }
    bid -= G_CONV_BIG;
    if (bid < G_CONV_SM) { dev_convT(bid, th1, Bt_th1, 64); return; }
    bid -= G_CONV_SM;
    dev_convT(bid, th2, Bt_th2, 64);
}

// P1: Kb1 + P-GEMM + offsets(hedge) + offsets(cell)
__global__ __launch_bounds__(256) void k_p1(const float* __restrict__ vac_emb,
                                            const u16* __restrict__ Bt_fhi,
                                            const float* __restrict__ fhi_b, float* __restrict__ P,
                                            const int* __restrict__ counts,
                                            int* __restrict__ chunk_off, int* __restrict__ range_total,
                                            const int* __restrict__ inc_hedge,
                                            const int* __restrict__ node2cell,
                                            int* __restrict__ he_off, int* __restrict__ cell_off) {
    __shared__ int lds[256];
    int bid = blockIdx.x;
    if (bid < G_KB1) { dev_kb1(bid, counts, chunk_off, range_total, lds); return; }
    bid -= G_KB1;
    if (bid < G_PGEMM) {
        int wid = bid * 4 + ((int)threadIdx.x >> 6);
        dev_gemm_direct<0, 0, D_IN>(wid, vac_emb, nullptr, Bt_fhi, fhi_b, P, VOCAB);
        return;
    }
    bid -= G_PGEMM;
    if (bid < G_OFF_HE) { dev_offsets(bid, inc_hedge, N_INC, N_HE, he_off); return; }
    bid -= G_OFF_HE;
    dev_offsets(bid, node2cell, N_NODES, N_CELLS, cell_off);
}

// P2: Kc + xt-GEMM L1 (gather-A) + x0-GEMM
__global__ __launch_bounds__(256) void k_p2(const float* __restrict__ P,
                                            const int* __restrict__ tok,
                                            const u16* __restrict__ Bt_th1, u16* __restrict__ xt,
                                            const float* __restrict__ x, const u16* __restrict__ Bt_fin,
                                            const float* __restrict__ fin_b, float* __restrict__ x0,
                                            const int* __restrict__ inc_node,
                                            const int* __restrict__ inc_hedge,
                                            const int* __restrict__ chunk_off,
                                            int2* __restrict__ bucket) {
    __shared__ int lds[512];
    int bid = blockIdx.x;
    if (bid < G_KC) { dev_kc(bid, inc_node, inc_hedge, chunk_off, bucket, lds); return; }
    bid -= G_KC;
    if (bid < G_XT) {
        int wid = bid * 4 + ((int)threadIdx.x >> 6);
        dev_gemm_direct<1, 1, 64>(wid, P, tok, Bt_th1, nullptr, xt, N_NODES);
        return;
    }
    bid -= G_XT;
    {
        int wid = bid * 4 + ((int)threadIdx.x >> 6);
        dev_gemm_direct<0, 0, D_IN>(wid, x, nullptr, Bt_fin, fin_b, x0, I_ * J_);
    }
}

// P3: Kd FIRST (overlaps under hedge_sum) + hedge_sum L1 (4 groups/block)
__global__ __launch_bounds__(256) void k_p3(const int* __restrict__ inc_node,
                                            const int* __restrict__ he_off,
                                            const u16* __restrict__ xt, u16* __restrict__ he,
                                            const int2* __restrict__ bucket,
                                            const int* __restrict__ range_total,
                                            int* __restrict__ node_off, int* __restrict__ node_deg,
                                            int* __restrict__ csr) {
    __shared__ int lds[1792];
    int bid = blockIdx.x;
    if (bid < G_KD) { dev_kd(bid, bucket, range_total, node_off, node_deg, csr, lds); return; }
    bid -= G_KD;
    for (int t = 0; t < 4; ++t)
        dev_hedge_sum(bid + t * HED_BLK, inc_node, he_off, xt, he);
}

// P6: hedge_sum L2 standalone (4 groups/block)
__global__ __launch_bounds__(256) void k_hedge_sum(const int* __restrict__ inc_node,
                                                   const int* __restrict__ he_off,
                                                   const u16* __restrict__ xt,
                                                   u16* __restrict__ he) {
    for (int t = 0; t < 4; ++t)
        dev_hedge_sum(blockIdx.x + t * HED_BLK, inc_node, he_off, xt, he);
}

// ---------------------------------------------------------------------------
// P8: pool (one cell/block, 800 blocks — parallelism preserved)
// ---------------------------------------------------------------------------
__global__ __launch_bounds__(256) void k_pool(const float* __restrict__ gx,
                                              const int* __restrict__ cell_off,
                                              const float* __restrict__ x0,
                                              float* __restrict__ out1) {
    __shared__ float ssum[4][64];
    __shared__ float smax[4][64];
    int c = blockIdx.x;
    int lane = threadIdx.x & 63;
    int w = threadIdx.x >> 6;
    int s = cell_off[c], e = cell_off[c + 1];
    float sum = 0.f, mx = -INFINITY;
    for (int n = s + w; n < e; n += 4) {
        float v = gx[((size_t)n << 6) + lane];
        sum += v;
        mx = fmaxf(mx, v);
    }
    ssum[w][lane] = sum;
    smax[w][lane] = mx;
    __syncthreads();
    if (w == 0) {
        sum = ssum[0][lane] + ssum[1][lane] + ssum[2][lane] + ssum[3][lane];
        mx = fmaxf(fmaxf(smax[0][lane], smax[1][lane]), fmaxf(smax[2][lane], smax[3][lane]));
        int cnt = e - s;
        float mean = (cnt > 0) ? sum / (float)cnt : 0.f;
        float mp = (cnt > 0) ? mx : 0.f;
        float ce = 0.5f * (mean + mp);
        out1[((size_t)c << 6) + lane] = x0[((size_t)c << 6) + lane] + 0.3f * ce;
    }
}

// ---------------------------------------------------------------------------
// P9: TCN (100 blocks, reads out1)
// ---------------------------------------------------------------------------
__global__ __launch_bounds__(256) void k_tcn(
    const float* __restrict__ xu,
    const float* __restrict__ wc1, const float* __restrict__ bc1, const float* __restrict__ g1,
    const float* __restrict__ be1, const float* __restrict__ m1, const float* __restrict__ v1,
    const float* __restrict__ wc2, const float* __restrict__ bc2, const float* __restrict__ g2,
    const float* __restrict__ be2, const float* __restrict__ m2, const float* __restrict__ v2,
    const float* __restrict__ wc3, const float* __restrict__ bc3, const float* __restrict__ g3,
    const float* __restrict__ be3, const float* __restrict__ m3, const float* __restrict__ v3,
    const float* __restrict__ fct_w, const float* __restrict__ fct_b,
    float* __restrict__ out2) {
    __shared__ float w_lds[64 * 64 * 3];
    __shared__ float hA[64][10];
    __shared__ float hB[64][10];
    __shared__ float mo[64];

    int n = blockIdx.x, tid = threadIdx.x;

    if (tid < 64) {
        hA[tid][0] = 0.f; hA[tid][9] = 0.f;
        hB[tid][0] = 0.f; hB[tid][9] = 0.f;
    }
    #pragma unroll
    for (int l = tid; l < 512; l += 256) {
        int t = l >> 6, i = l & 63;
        hA[i][t + 1] = xu[(size_t)n * 512 + l];
    }

    const float* wcs[3] = {wc1, wc2, wc3};
    const float* bcs[3] = {bc1, bc2, bc3};
    const float* gs[3]  = {g1, g2, g3};
    const float* bes[3] = {be1, be2, be3};
    const float* ms[3]  = {m1, m2, m3};
    const float* vs[3]  = {v1, v2, v3};

    float (*hin)[10] = hA;
    float (*hout)[10] = hB;

    #pragma unroll
    for (int li = 0; li < 3; ++li) {
        for (int l = tid; l < 64 * 64 * 3; l += 256) w_lds[l] = wcs[li][l];
        __syncthreads();
        #pragma unroll
        for (int rep = 0; rep < 2; ++rep) {
            int idx = tid + rep * 256;
            int o = idx >> 3, t = idx & 7;
            float acc = bcs[li][o];
            #pragma unroll 8
            for (int i = 0; i < 64; ++i) {
                const float* wr = &w_lds[o * 192 + i * 3];
                acc = fmaf(hin[i][t + 0], wr[0], acc);
                acc = fmaf(hin[i][t + 1], wr[1], acc);
                acc = fmaf(hin[i][t + 2], wr[2], acc);
            }
            acc = fmaxf(acc, 0.f);
            float sc = gs[li][o] * rsqrtf(vs[li][o] + 1e-5f);
            acc = (acc - ms[li][o]) * sc + bes[li][o];
            hout[o][t + 1] = acc;
        }
        __syncthreads();
        float (*tmp)[10] = hin; hin = hout; hout = tmp;
    }

    if (tid < 64) {
        float s = 0.f;
        #pragma unroll
        for (int t = 0; t < 8; ++t) s += hin[tid][t + 1];
        mo[tid] = s * 0.125f;
    }
    __syncthreads();
    if (tid < 64) {
        float acc = fct_b[tid];
        #pragma unroll 8
        for (int o = 0; o < 64; ++o) acc = fmaf(mo[o], fct_w[o * 64 + tid], acc);
        out2[(size_t)n * 64 + tid] = acc;
    }
}

// ---------------------------------------------------------------------------
extern "C" void kernel_launch(void* const* d_in, const int* in_sizes, int n_in,
                              void* d_out, int out_size, void* d_ws, size_t ws_size,
                              hipStream_t stream) {
    (void)in_sizes; (void)n_in; (void)out_size; (void)ws_size;

    const float* x          = (const float*)d_in[0];
    const int*   node_tok   = (const int*)d_in[1];
    const int*   inc_node   = (const int*)d_in[2];
    const int*   inc_hedge  = (const int*)d_in[3];
    const int*   node2cell  = (const int*)d_in[4];
    const float* vac_emb    = (const float*)d_in[5];
    const float* fhi_w      = (const float*)d_in[6];
    const float* fhi_b      = (const float*)d_in[7];
    const float* fin_w      = (const float*)d_in[8];
    const float* fin_b      = (const float*)d_in[9];
    const float* th1        = (const float*)d_in[10];
    const float* b1         = (const float*)d_in[11];
    const float* th2        = (const float*)d_in[12];
    const float* b2         = (const float*)d_in[13];
    const float* fct_w      = (const float*)d_in[32];
    const float* fct_b      = (const float*)d_in[33];

    char* ws = (char*)d_ws;
    size_t off = 0;
    float* P        = (float*)(ws + off); off += (size_t)VOCAB * 64 * 4;
    float* hbuf     = (float*)(ws + off); off += (size_t)N_NODES * 64 * 4;
    u16*   xt       = (u16*)(ws + off);   off += (size_t)N_NODES * 64 * 2;
    u16*   he       = (u16*)(ws + off);   off += (size_t)N_HE * 64 * 2;
    int2*  bucket   = (int2*)(ws + off);  off += (size_t)NRANGE * SLAB * 8;   // 16.8 MB
    int*   csr      = (int*)(ws + off);   off += (size_t)NRANGE * SLAB * 4;   //  8.4 MB
    float* x0       = (float*)(ws + off); off += (size_t)N_CELLS * 64 * 4;
    u16*   Bt_fhi   = (u16*)(ws + off);   off += (size_t)64 * D_IN * 2;
    u16*   Bt_fin   = (u16*)(ws + off);   off += (size_t)64 * D_IN * 2;
    u16*   Bt_th1   = (u16*)(ws + off);   off += (size_t)64 * 64 * 2;
    u16*   Bt_th2   = (u16*)(ws + off);   off += (size_t)64 * 64 * 2;
    int*   he_off   = (int*)(ws + off);   off += ((size_t)(N_HE + 1) * 4 + 255) / 256 * 256;
    int*   node_off = (int*)(ws + off);   off += (size_t)N_NODES * 4;
    int*   node_deg = (int*)(ws + off);   off += (size_t)N_NODES * 4;
    int*   cell_off = (int*)(ws + off);   off += ((size_t)(N_CELLS + 1) * 4 + 255) / 256 * 256;

    // counts/chunk_off/range_total alias hbuf (consumed by P1/P2/P3;
    // hbuf first written by node_sum L2 in P7)
    int*  counts      = (int*)hbuf;                       // [NCHUNK][256] 1.02 MB
    int*  chunk_off   = counts + NCHUNK * NRANGE;         // [NCHUNK][256] 1.02 MB
    int*  range_total = chunk_off + NCHUNK * NRANGE;      // [256]

    float* out1 = (float*)d_out;
    float* out2 = out1 + (size_t)I_ * J_ * D_H;

    // P0: Ka + convT x4
    k_p0<<<G_KA + 2 * G_CONV_BIG + 2 * G_CONV_SM, 256, 0, stream>>>(
        fhi_w, fin_w, th1, th2, Bt_fhi, Bt_fin, Bt_th1, Bt_th2,
        inc_node, counts);

    // P1: Kb1 + P-GEMM + offsets(hedge) + offsets(cell)
    k_p1<<<G_KB1 + G_PGEMM + G_OFF_HE + G_OFF_CELL, 256, 0, stream>>>(
        vac_emb, Bt_fhi, fhi_b, P, counts, chunk_off, range_total,
        inc_hedge, node2cell, he_off, cell_off);

    // P2: Kc + xt-GEMM L1 (gather-A) + x0-GEMM
    k_p2<<<G_KC + G_XT + G_X0, 256, 0, stream>>>(
        P, node_tok, Bt_th1, xt, x, Bt_fin, fin_b, x0,
        inc_node, inc_hedge, chunk_off, bucket);

    // P3: Kd (first, overlapped) + hedge_sum L1 (4 groups/block)
    k_p3<<<G_KD + HED_BLK, 256, 0, stream>>>(inc_node, he_off, xt, he,
                                             bucket, range_total, node_off, node_deg, csr);

    // P4: fused node_sum L1 + th2 MFMA -> xt (4 tiles/block)
    k_node_xt<<<NXT_BLK, 256, 0, stream>>>(csr, node_off, node_deg, he, b1, P, node_tok,
                                           Bt_th2, xt);

    // P6: hedge_sum L2 (4 groups/block)
    k_hedge_sum<<<HED_BLK, 256, 0, stream>>>(inc_node, he_off, xt, he);

    // P7: node_sum L2 -> hbuf = gx (4 groups/block)
    k_node_sum<<<NOD_BLK, 256, 0, stream>>>(csr, node_off, node_deg, he, b2, P, node_tok, hbuf);

    // P8: pool + fuse -> out1 (800 blocks)
    k_pool<<<N_CELLS, 256, 0, stream>>>(hbuf, cell_off, x0, out1);

    // P9: TCN -> out2
    k_tcn<<<I_, 256, 0, stream>>>(out1,
        (const float*)d_in[14], (const float*)d_in[15], (const float*)d_in[16],
        (const float*)d_in[17], (const float*)d_in[18], (const float*)d_in[19],
        (const float*)d_in[20], (const float*)d_in[21], (const float*)d_in[22],
        (const float*)d_in[23], (const float*)d_in[24], (const float*)d_in[25],
        (const float*)d_in[26], (const float*)d_in[27], (const float*)d_in[28],
        (const float*)d_in[29], (const float*)d_in[30], (const float*)d_in[31],
        fct_w, fct_b, out2);
}

// Round 14
// 473.906 us; speedup vs baseline: 1.0480x; 1.0480x over previous
//
#include <hip/hip_runtime.h>
#include <hip/hip_bf16.h>
#include <cstdint>
#include <cstddef>

#define I_      100
#define J_      8
#define D_IN    768
#define D_H     64
#define N_NODES 160000
#define N_HE    320000
#define N_INC   1600000
#define N_CELLS 800
#define VOCAB   30000

#define NRANGE   256
#define NPR      625
#define SLAB     8192            // per-range bucket/csr slab (Poisson(6250), 24 sigma)
#define NCHUNK   1000            // Ka/Kc scatter chunks (4 blocks/CU latency hiding)
#define EPB      (N_INC / NCHUNK)   // 1600

typedef unsigned short u16;
using short8 = __attribute__((ext_vector_type(8))) short;
using f32x4  = __attribute__((ext_vector_type(4))) float;

__device__ __forceinline__ float bf2f(u16 u) {
    union { uint32_t i; float f; } x; x.i = ((uint32_t)u) << 16; return x.f;
}
__device__ __forceinline__ u16 f2bf(float f) {
    union { float f; uint32_t i; } x; x.f = f;
    uint32_t b = x.i;
    b += 0x7FFFu + ((b >> 16) & 1u);
    return (u16)(b >> 16);
}
__device__ __forceinline__ float lo_bf(uint32_t u) {
    union { uint32_t i; float f; } x; x.i = u << 16; return x.f;
}
__device__ __forceinline__ float hi_bf(uint32_t u) {
    union { uint32_t i; float f; } x; x.i = u & 0xFFFF0000u; return x.f;
}
__device__ __forceinline__ uint32_t pack_bf2(float a, float b) {
    return (uint32_t)f2bf(a) | ((uint32_t)f2bf(b) << 16);
}

// grid-partition constants
#define G_OFF_HE   (N_INC / 256)        // 6250
#define G_OFF_CELL (N_NODES / 256)      // 625
#define G_CONV_BIG ((D_IN * 64) / 256)  // 192
#define G_CONV_SM  ((64 * 64) / 256)    // 16
#define G_KA       NCHUNK               // 1000 per-chunk range histograms
#define G_KB1      256                  // per-range column scans
#define G_KC       NCHUNK               // 1000 bucket scatter
#define G_KD       256                  // per-range CSR hist+scan+place
#define G_PGEMM    ((VOCAB + 63) / 64)  // 469
#define G_PT1      ((VOCAB + 63) / 64)  // 469 (PT1 = P @ th1 over vocab rows)
#define G_X0       ((I_ * J_ + 63) / 64)// 13
#define G_HEDGE    (N_HE / 32)          // 10000
#define G_NODE     (N_NODES / 32)       // 5000
#define G_NXT      (N_NODES / 32)       // 5000 (fused node_sum+th2 MFMA)

// ---------------------------------------------------------------------------
__device__ __forceinline__ void dev_offsets(int bid, const int* __restrict__ sorted,
                                            int n, int nbins, int* __restrict__ off) {
    int i = bid * 256 + threadIdx.x;
    if (i >= n) return;
    int cur = sorted[i];
    int prev = (i == 0) ? -1 : sorted[i - 1];
    for (int b = prev + 1; b <= cur; ++b) off[b] = i;
    if (i == n - 1) {
        for (int b = cur + 1; b <= nbins; ++b) off[b] = n;
    }
}

__device__ __forceinline__ void dev_convT(int bid, const float* __restrict__ B,
                                          u16* __restrict__ Bt, int K) {
    int g = bid * 256 + threadIdx.x;
    if (g >= K * 64) return;
    int k = g >> 6, n = g & 63;
    Bt[(size_t)n * K + k] = f2bf(B[g]);
}

// ---------------------------------------------------------------------------
// bucket-sort CSR build: chunk-contiguous writes throughout, no global atomics
// ---------------------------------------------------------------------------
// Ka: per-chunk histogram of node ranges -> counts[chunk][256]
__device__ __forceinline__ void dev_ka(int bid, const int* __restrict__ inc_node,
                                       int* __restrict__ counts, int* __restrict__ lds) {
    int tid = threadIdx.x;
    lds[tid] = 0;
    __syncthreads();
    int s = bid * EPB, e = s + EPB;
    for (int i = s + tid; i < e; i += 256)
        atomicAdd(&lds[(unsigned)inc_node[i] / NPR], 1);
    __syncthreads();
    counts[bid * NRANGE + tid] = lds[tid];
}

// Kb1: one block per range r: scan counts[c][r] over c=0..NCHUNK-1
__device__ __forceinline__ void dev_kb1(int r, const int* __restrict__ counts,
                                        int* __restrict__ chunk_off,
                                        int* __restrict__ range_total,
                                        int* __restrict__ lds) {
    int tid = threadIdx.x;
    int c0 = tid * 4;
    int v0 = (c0     < NCHUNK) ? counts[(c0    ) * NRANGE + r] : 0;
    int v1 = (c0 + 1 < NCHUNK) ? counts[(c0 + 1) * NRANGE + r] : 0;
    int v2 = (c0 + 2 < NCHUNK) ? counts[(c0 + 2) * NRANGE + r] : 0;
    int v3 = (c0 + 3 < NCHUNK) ? counts[(c0 + 3) * NRANGE + r] : 0;
    int s = v0 + v1 + v2 + v3;
    lds[tid] = s;
    __syncthreads();
    #pragma unroll
    for (int d = 1; d < 256; d <<= 1) {
        int t = (tid >= d) ? lds[tid - d] : 0;
        __syncthreads();
        lds[tid] += t;
        __syncthreads();
    }
    int run = lds[tid] - s;
    if (c0     < NCHUNK) { chunk_off[(c0    ) * NRANGE + r] = run; run += v0; }
    if (c0 + 1 < NCHUNK) { chunk_off[(c0 + 1) * NRANGE + r] = run; run += v1; }
    if (c0 + 2 < NCHUNK) { chunk_off[(c0 + 2) * NRANGE + r] = run; run += v2; }
    if (c0 + 3 < NCHUNK) { chunk_off[(c0 + 3) * NRANGE + r] = run; run += v3; }
    if (tid == 255) range_total[r] = lds[255];
}

// Kc: scatter pairs into per-range slabs (chunk-contiguous writes)
__device__ __forceinline__ void dev_kc(int bid, const int* __restrict__ inc_node,
                                       const int* __restrict__ inc_hedge,
                                       const int* __restrict__ chunk_off,
                                       int2* __restrict__ bucket, int* __restrict__ lds) {
    int tid = threadIdx.x;
    int* co  = lds;
    int* cur = lds + 256;
    co[tid]  = tid * SLAB + chunk_off[bid * NRANGE + tid];
    cur[tid] = 0;
    __syncthreads();
    int s = bid * EPB, e = s + EPB;
    for (int i = s + tid; i < e; i += 256) {
        int v = inc_node[i];
        int h = inc_hedge[i];
        int rg = (unsigned)v / NPR;
        int rank = atomicAdd(&cur[rg], 1);
        bucket[co[rg] + rank] = make_int2(v, h);
    }
}

// Kd: per-range exact CSR placement; writes node_off + node_deg (all LDS-local)
// lds layout: hist[768] | tsum[256] | cur[768]  (1792 ints)
__device__ __forceinline__ void dev_kd(int r, const int2* __restrict__ bucket,
                                       const int* __restrict__ range_total,
                                       int* __restrict__ node_off, int* __restrict__ node_deg,
                                       int* __restrict__ csr, int* __restrict__ lds) {
    int tid = threadIdx.x;
    int* hist = lds;
    int* tsum = lds + 768;
    int* cur  = lds + 1024;
    for (int i = tid; i < 768; i += 256) { hist[i] = 0; cur[i] = 0; }
    __syncthreads();
    int lo = r * NPR;
    int pb = r * SLAB;
    int pe = pb + range_total[r];
    for (int i = pb + tid; i < pe; i += 256)
        atomicAdd(&hist[bucket[i].x - lo], 1);
    __syncthreads();
    int b3 = tid * 3;
    int a0 = hist[b3], a1 = hist[b3 + 1], a2 = hist[b3 + 2];
    int s = a0 + a1 + a2;
    tsum[tid] = s;
    __syncthreads();
    #pragma unroll
    for (int d = 1; d < 256; d <<= 1) {
        int t = (tid >= d) ? tsum[tid - d] : 0;
        __syncthreads();
        tsum[tid] += t;
        __syncthreads();
    }
    int excl = tsum[tid] - s;
    hist[b3]     = excl;
    hist[b3 + 1] = excl + a0;
    hist[b3 + 2] = excl + a0 + a1;
    __syncthreads();
    for (int v = tid; v < NPR; v += 256) {
        int h0 = hist[v];
        node_off[lo + v] = pb + h0;
        node_deg[lo + v] = hist[v + 1] - h0;   // hist[625] = range total (valid)
    }
    for (int i = pb + tid; i < pe; i += 256) {
        int2 p = bucket[i];
        int l = p.x - lo;
        int k = atomicAdd(&cur[l], 1);
        csr[pb + hist[l] + k] = p.y;
    }
}

// ---------------------------------------------------------------------------
// R8 row-split barrier-free MFMA GEMM: one wave owns 16 rows x 64 cols
// ---------------------------------------------------------------------------
template <int BF16_OUT, int GATHER, int KK>
__device__ __forceinline__ void dev_gemm_direct(int wid, const float* __restrict__ A,
                                                const int* __restrict__ tok,
                                                const u16* __restrict__ Bt,
                                                const float* __restrict__ bias,
                                                void* __restrict__ C, int M) {
    int lane = threadIdx.x & 63;
    int m16 = lane & 15, q = lane >> 4;
    int base = wid << 4;
    if (base >= M) return;
    int row = base + m16;
    const float* arow = GATHER ? (A + ((size_t)tok[row] << 6))
                               : (A + (size_t)row * KK);

    f32x4 acc0 = {0.f, 0.f, 0.f, 0.f};
    f32x4 acc1 = {0.f, 0.f, 0.f, 0.f};
    f32x4 acc2 = {0.f, 0.f, 0.f, 0.f};
    f32x4 acc3 = {0.f, 0.f, 0.f, 0.f};

    #pragma unroll 2
    for (int kt = 0; kt < KK; kt += 32) {
        const float* ap = arow + kt + q * 8;
        float4 av0 = *reinterpret_cast<const float4*>(ap);
        float4 av1 = *reinterpret_cast<const float4*>(ap + 4);
        short8 a;
        a[0] = (short)f2bf(av0.x); a[1] = (short)f2bf(av0.y);
        a[2] = (short)f2bf(av0.z); a[3] = (short)f2bf(av0.w);
        a[4] = (short)f2bf(av1.x); a[5] = (short)f2bf(av1.y);
        a[6] = (short)f2bf(av1.z); a[7] = (short)f2bf(av1.w);
        const u16* bp = Bt + (size_t)m16 * KK + kt + q * 8;
        short8 b0 = *reinterpret_cast<const short8*>(bp);
        short8 b1 = *reinterpret_cast<const short8*>(bp + (size_t)16 * KK);
        short8 b2 = *reinterpret_cast<const short8*>(bp + (size_t)32 * KK);
        short8 b3 = *reinterpret_cast<const short8*>(bp + (size_t)48 * KK);
        acc0 = __builtin_amdgcn_mfma_f32_16x16x32_bf16(a, b0, acc0, 0, 0, 0);
        acc1 = __builtin_amdgcn_mfma_f32_16x16x32_bf16(a, b1, acc1, 0, 0, 0);
        acc2 = __builtin_amdgcn_mfma_f32_16x16x32_bf16(a, b2, acc2, 0, 0, 0);
        acc3 = __builtin_amdgcn_mfma_f32_16x16x32_bf16(a, b3, acc3, 0, 0, 0);
    }

    f32x4 accs[4] = {acc0, acc1, acc2, acc3};
    #pragma unroll
    for (int r = 0; r < 4; ++r) {
        int gr = base + q * 4 + r;
        #pragma unroll
        for (int j = 0; j < 4; ++j) {
            int col = j * 16 + m16;
            float v = accs[j][r];
            if (!BF16_OUT) v += bias[col];
            if (BF16_OUT)
                ((u16*)C)[(size_t)gr * 64 + col] = f2bf(v);
            else
                ((float*)C)[(size_t)gr * 64 + col] = v;
        }
    }
}

// ---------------------------------------------------------------------------
// hedge_sum: one 8-lane subgroup per hedge (8 hedges/wave), 2-way MLP unroll
// TOK=1: rows gathered as src[tok[inc_node[j]]] (PT1 path, L2-resident 3.8MB)
// TOK=0: rows gathered as src[inc_node[j]]      (xt path, L2 layer)
// ---------------------------------------------------------------------------
template <int TOK>
__device__ __forceinline__ void dev_hedge_sum(int bid, const int* __restrict__ inc_node,
                                              const int* __restrict__ he_off,
                                              const u16* __restrict__ src,
                                              const int* __restrict__ tok,
                                              u16* __restrict__ he) {
    int w = (bid * 256 + (int)threadIdx.x) >> 6;
    int lane = threadIdx.x & 63;
    int sub = lane >> 3;
    int c8 = (lane & 7) << 3;
    int hedge = w * 8 + sub;
    if (hedge >= N_HE) return;
    int s = he_off[hedge], e = he_off[hedge + 1];

    float a0 = 0.f, a1 = 0.f, a2 = 0.f, a3 = 0.f;
    float a4 = 0.f, a5 = 0.f, a6 = 0.f, a7 = 0.f;
    float b0 = 0.f, b1 = 0.f, b2 = 0.f, b3 = 0.f;
    float b4 = 0.f, b5 = 0.f, b6 = 0.f, b7 = 0.f;

    int j = s;
    if ((e - s) & 1) {
        int v = inc_node[j];
        int r = TOK ? tok[v] : v;
        uint4 d = *reinterpret_cast<const uint4*>(src + (((size_t)r) << 6) + c8);
        a0 += lo_bf(d.x); a1 += hi_bf(d.x);
        a2 += lo_bf(d.y); a3 += hi_bf(d.y);
        a4 += lo_bf(d.z); a5 += hi_bf(d.z);
        a6 += lo_bf(d.w); a7 += hi_bf(d.w);
        ++j;
    }
    int r0 = 0, r1 = 0;
    if (j < e) {
        int va = inc_node[j], vb = inc_node[j + 1];
        r0 = TOK ? tok[va] : va;
        r1 = TOK ? tok[vb] : vb;
    }
    for (; j < e; j += 2) {
        int c0 = r0, c1 = r1;
        if (j + 2 < e) {
            int va = inc_node[j + 2], vb = inc_node[j + 3];
            r0 = TOK ? tok[va] : va;
            r1 = TOK ? tok[vb] : vb;
        }
        uint4 d0 = *reinterpret_cast<const uint4*>(src + (((size_t)c0) << 6) + c8);
        uint4 d1 = *reinterpret_cast<const uint4*>(src + (((size_t)c1) << 6) + c8);
        a0 += lo_bf(d0.x); a1 += hi_bf(d0.x);
        a2 += lo_bf(d0.y); a3 += hi_bf(d0.y);
        a4 += lo_bf(d0.z); a5 += hi_bf(d0.z);
        a6 += lo_bf(d0.w); a7 += hi_bf(d0.w);
        b0 += lo_bf(d1.x); b1 += hi_bf(d1.x);
        b2 += lo_bf(d1.y); b3 += hi_bf(d1.y);
        b4 += lo_bf(d1.z); b5 += hi_bf(d1.z);
        b6 += lo_bf(d1.w); b7 += hi_bf(d1.w);
    }
    a0 += b0; a1 += b1; a2 += b2; a3 += b3;
    a4 += b4; a5 += b5; a6 += b6; a7 += b7;

    float inv = (e > s) ? 1.f / (float)(e - s) : 0.f;
    uint4 o;
    o.x = pack_bf2(a0 * inv, a1 * inv);
    o.y = pack_bf2(a2 * inv, a3 * inv);
    o.z = pack_bf2(a4 * inv, a5 * inv);
    o.w = pack_bf2(a6 * inv, a7 * inv);
    *reinterpret_cast<uint4*>(he + (((size_t)hedge) << 6) + c8) = o;
}

// node_sum core: returns the 8 h1/gx values for this lane's 8 cols
__device__ __forceinline__ void dev_node_core(int node, const int* __restrict__ csr,
                                              const int* __restrict__ node_off,
                                              const int* __restrict__ node_deg,
                                              const u16* __restrict__ he,
                                              const float* __restrict__ bias,
                                              const float* __restrict__ P,
                                              const int* __restrict__ tok,
                                              int c8, float* __restrict__ o) {
    int s = node_off[node];
    int e = s + node_deg[node];

    float a0 = 0.f, a1 = 0.f, a2 = 0.f, a3 = 0.f;
    float a4 = 0.f, a5 = 0.f, a6 = 0.f, a7 = 0.f;
    float b0 = 0.f, b1 = 0.f, b2 = 0.f, b3 = 0.f;
    float b4 = 0.f, b5 = 0.f, b6 = 0.f, b7 = 0.f;

    int j = s;
    if ((e - s) & 1) {
        uint4 d = *reinterpret_cast<const uint4*>(he + (((size_t)csr[j]) << 6) + c8);
        a0 += lo_bf(d.x); a1 += hi_bf(d.x);
        a2 += lo_bf(d.y); a3 += hi_bf(d.y);
        a4 += lo_bf(d.z); a5 += hi_bf(d.z);
        a6 += lo_bf(d.w); a7 += hi_bf(d.w);
        ++j;
    }
    int i0 = 0, i1 = 0;
    if (j < e) { i0 = csr[j]; i1 = csr[j + 1]; }
    for (; j < e; j += 2) {
        int c0 = i0, c1 = i1;
        if (j + 2 < e) { i0 = csr[j + 2]; i1 = csr[j + 3]; }
        uint4 d0 = *reinterpret_cast<const uint4*>(he + (((size_t)c0) << 6) + c8);
        uint4 d1 = *reinterpret_cast<const uint4*>(he + (((size_t)c1) << 6) + c8);
        a0 += lo_bf(d0.x); a1 += hi_bf(d0.x);
        a2 += lo_bf(d0.y); a3 += hi_bf(d0.y);
        a4 += lo_bf(d0.z); a5 += hi_bf(d0.z);
        a6 += lo_bf(d0.w); a7 += hi_bf(d0.w);
        b0 += lo_bf(d1.x); b1 += hi_bf(d1.x);
        b2 += lo_bf(d1.y); b3 += hi_bf(d1.y);
        b4 += lo_bf(d1.z); b5 += hi_bf(d1.z);
        b6 += lo_bf(d1.w); b7 += hi_bf(d1.w);
    }
    a0 += b0; a1 += b1; a2 += b2; a3 += b3;
    a4 += b4; a5 += b5; a6 += b6; a7 += b7;

    float inv = (e > s) ? 1.f / (float)(e - s) : 0.f;
    const float* nfp = P + (((size_t)tok[node]) << 6) + c8;
    float4 nv0 = *reinterpret_cast<const float4*>(nfp);
    float4 nv1 = *reinterpret_cast<const float4*>(nfp + 4);
    o[0] = fmaxf(fmaf(a0, inv, bias[c8 + 0]), 0.f) + nv0.x;
    o[1] = fmaxf(fmaf(a1, inv, bias[c8 + 1]), 0.f) + nv0.y;
    o[2] = fmaxf(fmaf(a2, inv, bias[c8 + 2]), 0.f) + nv0.z;
    o[3] = fmaxf(fmaf(a3, inv, bias[c8 + 3]), 0.f) + nv0.w;
    o[4] = fmaxf(fmaf(a4, inv, bias[c8 + 4]), 0.f) + nv1.x;
    o[5] = fmaxf(fmaf(a5, inv, bias[c8 + 5]), 0.f) + nv1.y;
    o[6] = fmaxf(fmaf(a6, inv, bias[c8 + 6]), 0.f) + nv1.z;
    o[7] = fmaxf(fmaf(a7, inv, bias[c8 + 7]), 0.f) + nv1.w;
}

// ---------------------------------------------------------------------------
// P4 fused: node_sum L1 -> LDS bf16 tile -> th2 MFMA -> xt  (skips hbuf)
// 32 nodes/block; waves 0-1 run the 2x 16-row MFMA tiles
// ---------------------------------------------------------------------------
__global__ __launch_bounds__(256) void k_node_xt(const int* __restrict__ csr,
                                                 const int* __restrict__ node_off,
                                                 const int* __restrict__ node_deg,
                                                 const u16* __restrict__ he,
                                                 const float* __restrict__ bias,
                                                 const float* __restrict__ P,
                                                 const int* __restrict__ tok,
                                                 const u16* __restrict__ Bt,
                                                 u16* __restrict__ xt) {
    __shared__ u16 h1s[32][72];   // +8 pad: row stride 144B breaks 128B bank alias
    int tid = threadIdx.x;
    int w = tid >> 6;
    int lane = tid & 63;
    int sub = lane >> 3;
    int c8 = (lane & 7) << 3;
    int rowib = w * 8 + sub;                    // 0..31
    int node = blockIdx.x * 32 + rowib;         // N_NODES = 5000*32 exact

    float o[8];
    dev_node_core(node, csr, node_off, node_deg, he, bias, P, tok, c8, o);

    uint4 pk;
    pk.x = pack_bf2(o[0], o[1]);
    pk.y = pack_bf2(o[2], o[3]);
    pk.z = pack_bf2(o[4], o[5]);
    pk.w = pack_bf2(o[6], o[7]);
    *reinterpret_cast<uint4*>(&h1s[rowib][c8]) = pk;
    __syncthreads();

    if (w < 2) {
        int m16 = lane & 15, q = lane >> 4;
        int base = w * 16;
        f32x4 acc0 = {0.f, 0.f, 0.f, 0.f};
        f32x4 acc1 = {0.f, 0.f, 0.f, 0.f};
        f32x4 acc2 = {0.f, 0.f, 0.f, 0.f};
        f32x4 acc3 = {0.f, 0.f, 0.f, 0.f};
        #pragma unroll
        for (int kt = 0; kt < 64; kt += 32) {
            short8 a = *reinterpret_cast<const short8*>(&h1s[base + m16][kt + q * 8]);
            const u16* bp = Bt + (size_t)m16 * 64 + kt + q * 8;
            short8 b0 = *reinterpret_cast<const short8*>(bp);
            short8 b1 = *reinterpret_cast<const short8*>(bp + (size_t)16 * 64);
            short8 b2 = *reinterpret_cast<const short8*>(bp + (size_t)32 * 64);
            short8 b3 = *reinterpret_cast<const short8*>(bp + (size_t)48 * 64);
            acc0 = __builtin_amdgcn_mfma_f32_16x16x32_bf16(a, b0, acc0, 0, 0, 0);
            acc1 = __builtin_amdgcn_mfma_f32_16x16x32_bf16(a, b1, acc1, 0, 0, 0);
            acc2 = __builtin_amdgcn_mfma_f32_16x16x32_bf16(a, b2, acc2, 0, 0, 0);
            acc3 = __builtin_amdgcn_mfma_f32_16x16x32_bf16(a, b3, acc3, 0, 0, 0);
        }
        f32x4 accs[4] = {acc0, acc1, acc2, acc3};
        #pragma unroll
        for (int r = 0; r < 4; ++r) {
            int gr = blockIdx.x * 32 + base + q * 4 + r;
            #pragma unroll
            for (int jj = 0; jj < 4; ++jj) {
                int col = jj * 16 + m16;
                xt[(size_t)gr * 64 + col] = f2bf(accs[jj][r]);
            }
        }
    }
}

// node_sum standalone (L2): writes f32 gx rows
__global__ __launch_bounds__(256) void k_node_sum(const int* __restrict__ csr,
                                                  const int* __restrict__ node_off,
                                                  const int* __restrict__ node_deg,
                                                  const u16* __restrict__ he,
                                                  const float* __restrict__ bias,
                                                  const float* __restrict__ P,
                                                  const int* __restrict__ tok,
                                                  float* __restrict__ out) {
    int w = (blockIdx.x * 256 + (int)threadIdx.x) >> 6;
    int lane = threadIdx.x & 63;
    int sub = lane >> 3;
    int c8 = (lane & 7) << 3;
    int node = w * 8 + sub;
    if (node >= N_NODES) return;
    float o[8];
    dev_node_core(node, csr, node_off, node_deg, he, bias, P, tok, c8, o);
    float* op = out + (((size_t)node) << 6) + c8;
    float4 o0 = make_float4(o[0], o[1], o[2], o[3]);
    float4 o1 = make_float4(o[4], o[5], o[6], o[7]);
    *reinterpret_cast<float4*>(op) = o0;
    *reinterpret_cast<float4*>(op + 4) = o1;
}

// ---------------------------------------------------------------------------
// phase mega-kernels (tail sub-kernels get LOWEST blockIdx so they start at t=0)
// ---------------------------------------------------------------------------
// P0: Ka + convT x4
__global__ __launch_bounds__(256) void k_p0(const float* __restrict__ fhi_w,
                                            const float* __restrict__ fin_w,
                                            const float* __restrict__ th1,
                                            const float* __restrict__ th2,
                                            u16* __restrict__ Bt_fhi, u16* __restrict__ Bt_fin,
                                            u16* __restrict__ Bt_th1, u16* __restrict__ Bt_th2,
                                            const int* __restrict__ inc_node,
                                            int* __restrict__ counts) {
    __shared__ int lds[256];
    int bid = blockIdx.x;
    if (bid < G_KA) { dev_ka(bid, inc_node, counts, lds); return; }
    bid -= G_KA;
    if (bid < G_CONV_BIG) { dev_convT(bid, fhi_w, Bt_fhi, D_IN); return; }
    bid -= G_CONV_BIG;
    if (bid < G_CONV_BIG) { dev_convT(bid, fin_w, Bt_fin, D_IN); return; }
    bid -= G_CONV_BIG;
    if (bid < G_CONV_SM) { dev_convT(bid, th1, Bt_th1, 64); return; }
    bid -= G_CONV_SM;
    dev_convT(bid, th2, Bt_th2, 64);
}

// P1: Kb1 + P-GEMM + offsets(hedge) + offsets(cell)
__global__ __launch_bounds__(256) void k_p1(const float* __restrict__ vac_emb,
                                            const u16* __restrict__ Bt_fhi,
                                            const float* __restrict__ fhi_b, float* __restrict__ P,
                                            const int* __restrict__ counts,
                                            int* __restrict__ chunk_off, int* __restrict__ range_total,
                                            const int* __restrict__ inc_hedge,
                                            const int* __restrict__ node2cell,
                                            int* __restrict__ he_off, int* __restrict__ cell_off) {
    __shared__ int lds[256];
    int bid = blockIdx.x;
    if (bid < G_KB1) { dev_kb1(bid, counts, chunk_off, range_total, lds); return; }
    bid -= G_KB1;
    if (bid < G_PGEMM) {
        int wid = bid * 4 + ((int)threadIdx.x >> 6);
        dev_gemm_direct<0, 0, D_IN>(wid, vac_emb, nullptr, Bt_fhi, fhi_b, P, VOCAB);
        return;
    }
    bid -= G_PGEMM;
    if (bid < G_OFF_HE) { dev_offsets(bid, inc_hedge, N_INC, N_HE, he_off); return; }
    bid -= G_OFF_HE;
    dev_offsets(bid, node2cell, N_NODES, N_CELLS, cell_off);
}

// P2: Kc + PT1-GEMM (vocab rows, 5.3x less work than per-node gather-GEMM) + x0
__global__ __launch_bounds__(256) void k_p2(const float* __restrict__ P,
                                            const u16* __restrict__ Bt_th1, u16* __restrict__ PT1,
                                            const float* __restrict__ x, const u16* __restrict__ Bt_fin,
                                            const float* __restrict__ fin_b, float* __restrict__ x0,
                                            const int* __restrict__ inc_node,
                                            const int* __restrict__ inc_hedge,
                                            const int* __restrict__ chunk_off,
                                            int2* __restrict__ bucket) {
    __shared__ int lds[512];
    int bid = blockIdx.x;
    if (bid < G_KC) { dev_kc(bid, inc_node, inc_hedge, chunk_off, bucket, lds); return; }
    bid -= G_KC;
    if (bid < G_PT1) {
        int wid = bid * 4 + ((int)threadIdx.x >> 6);
        dev_gemm_direct<1, 0, 64>(wid, P, nullptr, Bt_th1, nullptr, PT1, VOCAB);
        return;
    }
    bid -= G_PT1;
    {
        int wid = bid * 4 + ((int)threadIdx.x >> 6);
        dev_gemm_direct<0, 0, D_IN>(wid, x, nullptr, Bt_fin, fin_b, x0, I_ * J_);
    }
}

// P3: Kd FIRST (overlaps under hedge_sum) + hedge_sum L1 (PT1 + tok indirection)
__global__ __launch_bounds__(256) void k_p3(const int* __restrict__ inc_node,
                                            const int* __restrict__ he_off,
                                            const u16* __restrict__ PT1,
                                            const int* __restrict__ tok,
                                            u16* __restrict__ he,
                                            const int2* __restrict__ bucket,
                                            const int* __restrict__ range_total,
                                            int* __restrict__ node_off, int* __restrict__ node_deg,
                                            int* __restrict__ csr) {
    __shared__ int lds[1792];
    int bid = blockIdx.x;
    if (bid < G_KD) { dev_kd(bid, bucket, range_total, node_off, node_deg, csr, lds); return; }
    bid -= G_KD;
    dev_hedge_sum<1>(bid, inc_node, he_off, PT1, tok, he);
}

// P6: hedge_sum L2 (xt path, no indirection)
__global__ __launch_bounds__(256) void k_hedge_sum(const int* __restrict__ inc_node,
                                                   const int* __restrict__ he_off,
                                                   const u16* __restrict__ xt,
                                                   u16* __restrict__ he) {
    dev_hedge_sum<0>(blockIdx.x, inc_node, he_off, xt, nullptr, he);
}

// ---------------------------------------------------------------------------
// P8: pool (one cell/block, 800 blocks — parallelism preserved)
// ---------------------------------------------------------------------------
__global__ __launch_bounds__(256) void k_pool(const float* __restrict__ gx,
                                              const int* __restrict__ cell_off,
                                              const float* __restrict__ x0,
                                              float* __restrict__ out1) {
    __shared__ float ssum[4][64];
    __shared__ float smax[4][64];
    int c = blockIdx.x;
    int lane = threadIdx.x & 63;
    int w = threadIdx.x >> 6;
    int s = cell_off[c], e = cell_off[c + 1];
    float sum = 0.f, mx = -INFINITY;
    for (int n = s + w; n < e; n += 4) {
        float v = gx[((size_t)n << 6) + lane];
        sum += v;
        mx = fmaxf(mx, v);
    }
    ssum[w][lane] = sum;
    smax[w][lane] = mx;
    __syncthreads();
    if (w == 0) {
        sum = ssum[0][lane] + ssum[1][lane] + ssum[2][lane] + ssum[3][lane];
        mx = fmaxf(fmaxf(smax[0][lane], smax[1][lane]), fmaxf(smax[2][lane], smax[3][lane]));
        int cnt = e - s;
        float mean = (cnt > 0) ? sum / (float)cnt : 0.f;
        float mp = (cnt > 0) ? mx : 0.f;
        float ce = 0.5f * (mean + mp);
        out1[((size_t)c << 6) + lane] = x0[((size_t)c << 6) + lane] + 0.3f * ce;
    }
}

// ---------------------------------------------------------------------------
// P9: TCN (100 blocks, reads out1)
// ---------------------------------------------------------------------------
__global__ __launch_bounds__(256) void k_tcn(
    const float* __restrict__ xu,
    const float* __restrict__ wc1, const float* __restrict__ bc1, const float* __restrict__ g1,
    const float* __restrict__ be1, const float* __restrict__ m1, const float* __restrict__ v1,
    const float* __restrict__ wc2, const float* __restrict__ bc2, const float* __restrict__ g2,
    const float* __restrict__ be2, const float* __restrict__ m2, const float* __restrict__ v2,
    const float* __restrict__ wc3, const float* __restrict__ bc3, const float* __restrict__ g3,
    const float* __restrict__ be3, const float* __restrict__ m3, const float* __restrict__ v3,
    const float* __restrict__ fct_w, const float* __restrict__ fct_b,
    float* __restrict__ out2) {
    __shared__ float w_lds[64 * 64 * 3];
    __shared__ float hA[64][10];
    __shared__ float hB[64][10];
    __shared__ float mo[64];

    int n = blockIdx.x, tid = threadIdx.x;

    if (tid < 64) {
        hA[tid][0] = 0.f; hA[tid][9] = 0.f;
        hB[tid][0] = 0.f; hB[tid][9] = 0.f;
    }
    #pragma unroll
    for (int l = tid; l < 512; l += 256) {
        int t = l >> 6, i = l & 63;
        hA[i][t + 1] = xu[(size_t)n * 512 + l];
    }

    const float* wcs[3] = {wc1, wc2, wc3};
    const float* bcs[3] = {bc1, bc2, bc3};
    const float* gs[3]  = {g1, g2, g3};
    const float* bes[3] = {be1, be2, be3};
    const float* ms[3]  = {m1, m2, m3};
    const float* vs[3]  = {v1, v2, v3};

    float (*hin)[10] = hA;
    float (*hout)[10] = hB;

    #pragma unroll
    for (int li = 0; li < 3; ++li) {
        for (int l = tid; l < 64 * 64 * 3; l += 256) w_lds[l] = wcs[li][l];
        __syncthreads();
        #pragma unroll
        for (int rep = 0; rep < 2; ++rep) {
            int idx = tid + rep * 256;
            int o = idx >> 3, t = idx & 7;
            float acc = bcs[li][o];
            #pragma unroll 8
            for (int i = 0; i < 64; ++i) {
                const float* wr = &w_lds[o * 192 + i * 3];
                acc = fmaf(hin[i][t + 0], wr[0], acc);
                acc = fmaf(hin[i][t + 1], wr[1], acc);
                acc = fmaf(hin[i][t + 2], wr[2], acc);
            }
            acc = fmaxf(acc, 0.f);
            float sc = gs[li][o] * rsqrtf(vs[li][o] + 1e-5f);
            acc = (acc - ms[li][o]) * sc + bes[li][o];
            hout[o][t + 1] = acc;
        }
        __syncthreads();
        float (*tmp)[10] = hin; hin = hout; hout = tmp;
    }

    if (tid < 64) {
        float s = 0.f;
        #pragma unroll
        for (int t = 0; t < 8; ++t) s += hin[tid][t + 1];
        mo[tid] = s * 0.125f;
    }
    __syncthreads();
    if (tid < 64) {
        float acc = fct_b[tid];
        #pragma unroll 8
        for (int o = 0; o < 64; ++o) acc = fmaf(mo[o], fct_w[o * 64 + tid], acc);
        out2[(size_t)n * 64 + tid] = acc;
    }
}

// ---------------------------------------------------------------------------
extern "C" void kernel_launch(void* const* d_in, const int* in_sizes, int n_in,
                              void* d_out, int out_size, void* d_ws, size_t ws_size,
                              hipStream_t stream) {
    (void)in_sizes; (void)n_in; (void)out_size; (void)ws_size;

    const float* x          = (const float*)d_in[0];
    const int*   node_tok   = (const int*)d_in[1];
    const int*   inc_node   = (const int*)d_in[2];
    const int*   inc_hedge  = (const int*)d_in[3];
    const int*   node2cell  = (const int*)d_in[4];
    const float* vac_emb    = (const float*)d_in[5];
    const float* fhi_w      = (const float*)d_in[6];
    const float* fhi_b      = (const float*)d_in[7];
    const float* fin_w      = (const float*)d_in[8];
    const float* fin_b      = (const float*)d_in[9];
    const float* th1        = (const float*)d_in[10];
    const float* b1         = (const float*)d_in[11];
    const float* th2        = (const float*)d_in[12];
    const float* b2         = (const float*)d_in[13];
    const float* fct_w      = (const float*)d_in[32];
    const float* fct_b      = (const float*)d_in[33];

    char* ws = (char*)d_ws;
    size_t off = 0;
    float* P        = (float*)(ws + off); off += (size_t)VOCAB * 64 * 4;
    float* hbuf     = (float*)(ws + off); off += (size_t)N_NODES * 64 * 4;
    u16*   xt       = (u16*)(ws + off);   off += (size_t)N_NODES * 64 * 2;
    u16*   he       = (u16*)(ws + off);   off += (size_t)N_HE * 64 * 2;
    int2*  bucket   = (int2*)(ws + off);  off += (size_t)NRANGE * SLAB * 8;   // 16.8 MB
    int*   csr      = (int*)(ws + off);   off += (size_t)NRANGE * SLAB * 4;   //  8.4 MB
    float* x0       = (float*)(ws + off); off += (size_t)N_CELLS * 64 * 4;
    u16*   Bt_fhi   = (u16*)(ws + off);   off += (size_t)64 * D_IN * 2;
    u16*   Bt_fin   = (u16*)(ws + off);   off += (size_t)64 * D_IN * 2;
    u16*   Bt_th1   = (u16*)(ws + off);   off += (size_t)64 * 64 * 2;
    u16*   Bt_th2   = (u16*)(ws + off);   off += (size_t)64 * 64 * 2;
    int*   he_off   = (int*)(ws + off);   off += ((size_t)(N_HE + 1) * 4 + 255) / 256 * 256;
    int*   node_off = (int*)(ws + off);   off += (size_t)N_NODES * 4;
    int*   node_deg = (int*)(ws + off);   off += (size_t)N_NODES * 4;
    int*   cell_off = (int*)(ws + off);   off += ((size_t)(N_CELLS + 1) * 4 + 255) / 256 * 256;
    u16*   PT1      = (u16*)(ws + off);   off += (size_t)VOCAB * 64 * 2;      // 3.84 MB

    // counts/chunk_off/range_total alias hbuf (consumed by P1/P2/P3;
    // hbuf first written by node_sum L2 in P7)
    int*  counts      = (int*)hbuf;                       // [NCHUNK][256] 1.02 MB
    int*  chunk_off   = counts + NCHUNK * NRANGE;         // [NCHUNK][256] 1.02 MB
    int*  range_total = chunk_off + NCHUNK * NRANGE;      // [256]

    float* out1 = (float*)d_out;
    float* out2 = out1 + (size_t)I_ * J_ * D_H;

    // P0: Ka + convT x4
    k_p0<<<G_KA + 2 * G_CONV_BIG + 2 * G_CONV_SM, 256, 0, stream>>>(
        fhi_w, fin_w, th1, th2, Bt_fhi, Bt_fin, Bt_th1, Bt_th2,
        inc_node, counts);

    // P1: Kb1 + P-GEMM + offsets(hedge) + offsets(cell)
    k_p1<<<G_KB1 + G_PGEMM + G_OFF_HE + G_OFF_CELL, 256, 0, stream>>>(
        vac_emb, Bt_fhi, fhi_b, P, counts, chunk_off, range_total,
        inc_hedge, node2cell, he_off, cell_off);

    // P2: Kc + PT1-GEMM + x0-GEMM
    k_p2<<<G_KC + G_PT1 + G_X0, 256, 0, stream>>>(
        P, Bt_th1, PT1, x, Bt_fin, fin_b, x0,
        inc_node, inc_hedge, chunk_off, bucket);

    // P3: Kd (first, overlapped) + hedge_sum L1 (PT1[tok[.]] gather)
    k_p3<<<G_KD + G_HEDGE, 256, 0, stream>>>(inc_node, he_off, PT1, node_tok, he,
                                             bucket, range_total, node_off, node_deg, csr);

    // P4: fused node_sum L1 + th2 MFMA -> xt (hbuf round-trip eliminated)
    k_node_xt<<<G_NXT, 256, 0, stream>>>(csr, node_off, node_deg, he, b1, P, node_tok,
                                         Bt_th2, xt);

    // P6: hedge_sum L2
    k_hedge_sum<<<G_HEDGE, 256, 0, stream>>>(inc_node, he_off, xt, he);

    // P7: node_sum L2 -> hbuf = gx
    k_node_sum<<<G_NODE, 256, 0, stream>>>(csr, node_off, node_deg, he, b2, P, node_tok, hbuf);

    // P8: pool + fuse -> out1 (800 blocks)
    k_pool<<<N_CELLS, 256, 0, stream>>>(hbuf, cell_off, x0, out1);

    // P9: TCN -> out2
    k_tcn<<<I_, 256, 0, stream>>>(out1,
        (const float*)d_in[14], (const float*)d_in[15], (const float*)d_in[16],
        (const float*)d_in[17], (const float*)d_in[18], (const float*)d_in[19],
        (const float*)d_in[20], (const float*)d_in[21], (const float*)d_in[22],
        (const float*)d_in[23], (const float*)d_in[24], (const float*)d_in[25],
        (const float*)d_in[26], (const float*)d_in[27], (const float*)d_in[28],
        (const float*)d_in[29], (const float*)d_in[30], (const float*)d_in[31],
        fct_w, fct_b, out2);
}